// Round 1
// baseline (2198.498 us; speedup 1.0000x reference)
//
#include <hip/hip_runtime.h>
#include <math.h>

#define E_TOTAL 160000
#define N_NODES 10000
#define TE 32
#define NELEM_ 90
#define PRE_T_OFF (NELEM_ * 128)

// ---------------- pre-kernel: fold source/target embedding through w0 ----------------
// pre[0      .. 11520) = source_emb @ w0[128:256, :]   (90 x 128)
// pre[11520 .. 23040) = target_emb @ w0[256:384, :]   (90 x 128)
__global__ __launch_bounds__(256) void precompute_embw(
    const float* __restrict__ source_emb,
    const float* __restrict__ target_emb,
    const float* __restrict__ w0,
    float* __restrict__ pre) {
  int idx = blockIdx.x * 256 + threadIdx.x;
  if (idx >= 2 * NELEM_ * 128) return;
  int table = idx >= PRE_T_OFF ? 1 : 0;
  int rem = idx - table * PRE_T_OFF;
  int r = rem >> 7;
  int c = rem & 127;
  const float* emb = (table ? target_emb : source_emb) + r * 128;
  const float* w = w0 + (128 + table * 128) * 128 + c;
  float acc = 0.f;
#pragma unroll 4
  for (int k = 0; k < 128; ++k) acc += emb[k] * w[(size_t)k * 128];
  pre[idx] = acc;
}

__device__ __forceinline__ float silu_f(float v) {
  return v * (1.f / (1.f + __expf(-v)));
}

// LayerNorm stats across 128 cols spread over 32 col-group lanes (4 cols each).
// acc[i][j]: 4 edges x 4 cols held by this thread. Butterfly over 32-lane half.
__device__ __forceinline__ void ln_stats(float acc[4][4], float mu[4], float rstd[4]) {
  float s[4], q[4];
#pragma unroll
  for (int i = 0; i < 4; ++i) {
    s[i] = acc[i][0] + acc[i][1] + acc[i][2] + acc[i][3];
    q[i] = acc[i][0] * acc[i][0] + acc[i][1] * acc[i][1] +
           acc[i][2] * acc[i][2] + acc[i][3] * acc[i][3];
  }
#pragma unroll
  for (int off = 16; off >= 1; off >>= 1) {
#pragma unroll
    for (int i = 0; i < 4; ++i) {
      s[i] += __shfl_xor(s[i], off, 32);
      q[i] += __shfl_xor(q[i], off, 32);
    }
  }
#pragma unroll
  for (int i = 0; i < 4; ++i) {
    float m = s[i] * (1.f / 128.f);
    float var = q[i] * (1.f / 128.f) - m * m;
    mu[i] = m;
    rstd[i] = rsqrtf(var + 1e-5f);
  }
}

// ---------------- fused edge kernel ----------------
__global__ __launch_bounds__(256) void edge_fused(
    const int* __restrict__ atomic_numbers,
    const float* __restrict__ edge_distance,
    const int* __restrict__ edge_index,
    const float* __restrict__ envelope,
    const float* __restrict__ w0,
    const float* __restrict__ b0,
    const float* __restrict__ g0,
    const float* __restrict__ beta0,
    const float* __restrict__ w1,
    const float* __restrict__ b1,
    const float* __restrict__ g1,
    const float* __restrict__ beta1,
    const float* __restrict__ w2,
    const float* __restrict__ b2,
    const float* __restrict__ wig,
    const float* __restrict__ pre,
    float* __restrict__ out) {
  __shared__ float sHa[TE * 128];   // hidden after LN1+silu; later aliased as wigner stage
  __shared__ float sHb[TE * 128];   // dist tile; later hidden after LN2+silu
  __shared__ int s_srow[TE];
  __shared__ int s_trow[TE];
  __shared__ int s_tgt[TE];
  __shared__ float s_env[TE];

  const int tid = threadIdx.x;
  const int eg = tid >> 5;   // 0..7: edge group of 4
  const int cg = tid & 31;   // 0..31: col group
  const int eBlock = blockIdx.x * TE;
  const int eL0 = eg * 4;
  const int c0 = cg * 4;

  // ---- stage per-edge metadata + dist tile ----
  if (tid < TE) {
    int e = eBlock + tid;
    int dst = edge_index[E_TOTAL + e];
    s_srow[tid] = atomic_numbers[edge_index[e]];
    s_trow[tid] = atomic_numbers[dst];
    s_tgt[tid] = dst;
    s_env[tid] = envelope[e] * 0.2f;  // fold 1/RESCALE (linear)
  }
  {
    const float4* src4 = (const float4*)(edge_distance + (size_t)eBlock * 128);
    float4* dst4 = (float4*)sHb;
#pragma unroll
    for (int j = 0; j < 4; ++j) dst4[tid + 256 * j] = src4[tid + 256 * j];
  }
  __syncthreads();

  // ---- GEMM1: dist(32x128) @ w0[0:128](128x128) ----
  float acc[4][4];
#pragma unroll
  for (int i = 0; i < 4; ++i)
#pragma unroll
    for (int j = 0; j < 4; ++j) acc[i][j] = 0.f;
#pragma unroll 4
  for (int k = 0; k < 128; ++k) {
    float4 b = *(const float4*)(w0 + (size_t)k * 128 + c0);
    float a0 = sHb[(eL0 + 0) * 128 + k];
    float a1 = sHb[(eL0 + 1) * 128 + k];
    float a2 = sHb[(eL0 + 2) * 128 + k];
    float a3 = sHb[(eL0 + 3) * 128 + k];
    acc[0][0] += a0 * b.x; acc[0][1] += a0 * b.y; acc[0][2] += a0 * b.z; acc[0][3] += a0 * b.w;
    acc[1][0] += a1 * b.x; acc[1][1] += a1 * b.y; acc[1][2] += a1 * b.z; acc[1][3] += a1 * b.w;
    acc[2][0] += a2 * b.x; acc[2][1] += a2 * b.y; acc[2][2] += a2 * b.z; acc[2][3] += a2 * b.w;
    acc[3][0] += a3 * b.x; acc[3][1] += a3 * b.y; acc[3][2] += a3 * b.z; acc[3][3] += a3 * b.w;
  }
  __syncthreads();  // metadata visible; GEMM1 reads of sHb done

  // add gathered embedding projections + bias, LN1 + silu -> sHa
  {
    float4 bb = *(const float4*)(b0 + c0);
#pragma unroll
    for (int i = 0; i < 4; ++i) {
      float4 ps = *(const float4*)(pre + (size_t)s_srow[eL0 + i] * 128 + c0);
      float4 pt = *(const float4*)(pre + PRE_T_OFF + (size_t)s_trow[eL0 + i] * 128 + c0);
      acc[i][0] += ps.x + pt.x + bb.x;
      acc[i][1] += ps.y + pt.y + bb.y;
      acc[i][2] += ps.z + pt.z + bb.z;
      acc[i][3] += ps.w + pt.w + bb.w;
    }
    float mu[4], rstd[4];
    ln_stats(acc, mu, rstd);
    float4 g = *(const float4*)(g0 + c0);
    float4 be = *(const float4*)(beta0 + c0);
#pragma unroll
    for (int i = 0; i < 4; ++i) {
      float v0 = silu_f((acc[i][0] - mu[i]) * rstd[i] * g.x + be.x);
      float v1 = silu_f((acc[i][1] - mu[i]) * rstd[i] * g.y + be.y);
      float v2 = silu_f((acc[i][2] - mu[i]) * rstd[i] * g.z + be.z);
      float v3 = silu_f((acc[i][3] - mu[i]) * rstd[i] * g.w + be.w);
      *(float4*)(sHa + (eL0 + i) * 128 + c0) = make_float4(v0, v1, v2, v3);
    }
  }
  __syncthreads();

  // ---- GEMM2: h(32x128) @ w1(128x128) ----
#pragma unroll
  for (int i = 0; i < 4; ++i)
#pragma unroll
    for (int j = 0; j < 4; ++j) acc[i][j] = 0.f;
#pragma unroll 4
  for (int k = 0; k < 128; ++k) {
    float4 b = *(const float4*)(w1 + (size_t)k * 128 + c0);
    float a0 = sHa[(eL0 + 0) * 128 + k];
    float a1 = sHa[(eL0 + 1) * 128 + k];
    float a2 = sHa[(eL0 + 2) * 128 + k];
    float a3 = sHa[(eL0 + 3) * 128 + k];
    acc[0][0] += a0 * b.x; acc[0][1] += a0 * b.y; acc[0][2] += a0 * b.z; acc[0][3] += a0 * b.w;
    acc[1][0] += a1 * b.x; acc[1][1] += a1 * b.y; acc[1][2] += a1 * b.z; acc[1][3] += a1 * b.w;
    acc[2][0] += a2 * b.x; acc[2][1] += a2 * b.y; acc[2][2] += a2 * b.z; acc[2][3] += a2 * b.w;
    acc[3][0] += a3 * b.x; acc[3][1] += a3 * b.y; acc[3][2] += a3 * b.z; acc[3][3] += a3 * b.w;
  }
  {
    float4 bb = *(const float4*)(b1 + c0);
#pragma unroll
    for (int i = 0; i < 4; ++i) {
      acc[i][0] += bb.x; acc[i][1] += bb.y; acc[i][2] += bb.z; acc[i][3] += bb.w;
    }
    float mu[4], rstd[4];
    ln_stats(acc, mu, rstd);
    float4 g = *(const float4*)(g1 + c0);
    float4 be = *(const float4*)(beta1 + c0);
#pragma unroll
    for (int i = 0; i < 4; ++i) {
      float v0 = silu_f((acc[i][0] - mu[i]) * rstd[i] * g.x + be.x);
      float v1 = silu_f((acc[i][1] - mu[i]) * rstd[i] * g.y + be.y);
      float v2 = silu_f((acc[i][2] - mu[i]) * rstd[i] * g.z + be.z);
      float v3 = silu_f((acc[i][3] - mu[i]) * rstd[i] * g.w + be.w);
      *(float4*)(sHb + (eL0 + i) * 128 + c0) = make_float4(v0, v1, v2, v3);
    }
  }
  __syncthreads();  // sHb (h2) published; sHa free now

  // ---- stage compact wigner coeffs into sHa alias: sW[e][m][l<5], 32*125 floats ----
  float* sW = sHa;
  for (int j = tid; j < TE * 125; j += 256) {
    int e = j / 125;
    int r = j - e * 125;
    int m = r / 5;
    int l = r - m * 5;
    sW[j] = wig[(size_t)(eBlock + e) * 625 + m * 25 + l];
  }

  // ---- GEMM3: h2(32x128) @ w2(128x320); thread handles 4 edges x (5 l x 2 c) ----
  const int c2 = cg * 2;
  float acc3[4][5][2];
#pragma unroll
  for (int i = 0; i < 4; ++i)
#pragma unroll
    for (int l = 0; l < 5; ++l) { acc3[i][l][0] = 0.f; acc3[i][l][1] = 0.f; }
#pragma unroll 2
  for (int k = 0; k < 128; ++k) {
    float a0 = sHb[(eL0 + 0) * 128 + k];
    float a1 = sHb[(eL0 + 1) * 128 + k];
    float a2 = sHb[(eL0 + 2) * 128 + k];
    float a3 = sHb[(eL0 + 3) * 128 + k];
#pragma unroll
    for (int l = 0; l < 5; ++l) {
      float2 b = *(const float2*)(w2 + (size_t)k * 320 + l * 64 + c2);
      acc3[0][l][0] += a0 * b.x; acc3[0][l][1] += a0 * b.y;
      acc3[1][l][0] += a1 * b.x; acc3[1][l][1] += a1 * b.y;
      acc3[2][l][0] += a2 * b.x; acc3[2][l][1] += a2 * b.y;
      acc3[3][l][0] += a3 * b.x; acc3[3][l][1] += a3 * b.y;
    }
  }

  // bias + envelope (1/RESCALE folded)
#pragma unroll
  for (int l = 0; l < 5; ++l) {
    float2 bb = *(const float2*)(b2 + l * 64 + c2);
#pragma unroll
    for (int i = 0; i < 4; ++i) {
      float ev = s_env[eL0 + i];
      acc3[i][l][0] = (acc3[i][l][0] + bb.x) * ev;
      acc3[i][l][1] = (acc3[i][l][1] + bb.y) * ev;
    }
  }
  __syncthreads();  // sW staged; all sHb reads done

  // ---- wigner rotate in registers + atomic scatter ----
#pragma unroll
  for (int i = 0; i < 4; ++i) {
    float* po = out + (size_t)s_tgt[eL0 + i] * 1600 + c2;
    const float* pw = sW + (eL0 + i) * 125;
    for (int m = 0; m < 25; ++m) {
      float wv0 = pw[m * 5 + 0];
      float wv1 = pw[m * 5 + 1];
      float wv2 = pw[m * 5 + 2];
      float wv3 = pw[m * 5 + 3];
      float wv4 = pw[m * 5 + 4];
      float y0 = wv0 * acc3[i][0][0] + wv1 * acc3[i][1][0] + wv2 * acc3[i][2][0] +
                 wv3 * acc3[i][3][0] + wv4 * acc3[i][4][0];
      float y1 = wv0 * acc3[i][0][1] + wv1 * acc3[i][1][1] + wv2 * acc3[i][2][1] +
                 wv3 * acc3[i][3][1] + wv4 * acc3[i][4][1];
      __hip_atomic_fetch_add(po + m * 64, y0, __ATOMIC_RELAXED, __HIP_MEMORY_SCOPE_AGENT);
      __hip_atomic_fetch_add(po + m * 64 + 1, y1, __ATOMIC_RELAXED, __HIP_MEMORY_SCOPE_AGENT);
    }
  }
}

extern "C" void kernel_launch(void* const* d_in, const int* in_sizes, int n_in,
                              void* d_out, int out_size, void* d_ws, size_t ws_size,
                              hipStream_t stream) {
  const int* atomic_numbers = (const int*)d_in[0];
  const float* edge_distance = (const float*)d_in[1];
  const int* edge_index = (const int*)d_in[2];
  const float* envelope = (const float*)d_in[3];
  const float* source_emb = (const float*)d_in[4];
  const float* target_emb = (const float*)d_in[5];
  const float* w0 = (const float*)d_in[6];
  const float* b0 = (const float*)d_in[7];
  const float* g0 = (const float*)d_in[8];
  const float* beta0 = (const float*)d_in[9];
  const float* w1 = (const float*)d_in[10];
  const float* b1 = (const float*)d_in[11];
  const float* g1 = (const float*)d_in[12];
  const float* beta1 = (const float*)d_in[13];
  const float* w2 = (const float*)d_in[14];
  const float* b2 = (const float*)d_in[15];
  const float* wig = (const float*)d_in[16];
  float* pre = (float*)d_ws;
  float* out = (float*)d_out;

  hipMemsetAsync(d_out, 0, (size_t)out_size * sizeof(float), stream);
  precompute_embw<<<(2 * NELEM_ * 128 + 255) / 256, 256, 0, stream>>>(
      source_emb, target_emb, w0, pre);
  edge_fused<<<E_TOTAL / TE, 256, 0, stream>>>(
      atomic_numbers, edge_distance, edge_index, envelope, w0, b0, g0, beta0,
      w1, b1, g1, beta1, w2, b2, wig, pre, out);
}

// Round 2
// 1335.083 us; speedup vs baseline: 1.6467x; 1.6467x over previous
//
#include <hip/hip_runtime.h>
#include <hip/hip_bf16.h>
#include <math.h>

#define E_TOTAL 160000
#define N_NODES 10000
#define TE 32
#define NELEM_ 90
#define PRE_T_OFF (NELEM_ * 128)

// ---------------- pre-kernel: fold source/target embedding through w0 ----------------
__global__ __launch_bounds__(256) void precompute_embw(
    const float* __restrict__ source_emb,
    const float* __restrict__ target_emb,
    const float* __restrict__ w0,
    float* __restrict__ pre) {
  int idx = blockIdx.x * 256 + threadIdx.x;
  if (idx >= 2 * NELEM_ * 128) return;
  int table = idx >= PRE_T_OFF ? 1 : 0;
  int rem = idx - table * PRE_T_OFF;
  int r = rem >> 7;
  int c = rem & 127;
  const float* emb = (table ? target_emb : source_emb) + r * 128;
  const float* w = w0 + (128 + table * 128) * 128 + c;
  float acc = 0.f;
#pragma unroll 4
  for (int k = 0; k < 128; ++k) acc += emb[k] * w[(size_t)k * 128];
  pre[idx] = acc;
}

__device__ __forceinline__ float silu_f(float v) {
  return v * (1.f / (1.f + __expf(-v)));
}

__device__ __forceinline__ void ln_stats(float acc[4][4], float mu[4], float rstd[4]) {
  float s[4], q[4];
#pragma unroll
  for (int i = 0; i < 4; ++i) {
    s[i] = acc[i][0] + acc[i][1] + acc[i][2] + acc[i][3];
    q[i] = acc[i][0] * acc[i][0] + acc[i][1] * acc[i][1] +
           acc[i][2] * acc[i][2] + acc[i][3] * acc[i][3];
  }
#pragma unroll
  for (int off = 16; off >= 1; off >>= 1) {
#pragma unroll
    for (int i = 0; i < 4; ++i) {
      s[i] += __shfl_xor(s[i], off, 32);
      q[i] += __shfl_xor(q[i], off, 32);
    }
  }
#pragma unroll
  for (int i = 0; i < 4; ++i) {
    float m = s[i] * (1.f / 128.f);
    float var = q[i] * (1.f / 128.f) - m * m;
    mu[i] = m;
    rstd[i] = rsqrtf(var + 1e-5f);
  }
}

// ---------------- CSR build ----------------
__global__ __launch_bounds__(256) void count_kernel(const int* __restrict__ edge_index,
                                                    int* __restrict__ cnt) {
  int e = blockIdx.x * 256 + threadIdx.x;
  if (e < E_TOTAL) atomicAdd(&cnt[edge_index[E_TOTAL + e]], 1);
}

__global__ __launch_bounds__(1024) void scan_kernel(const int* __restrict__ cnt,
                                                    int* __restrict__ offsets,
                                                    int* __restrict__ cursor) {
  __shared__ int sums[1024];
  int t = threadIdx.x;
  int base = t * 10;
  int local[10];
  int tot = 0;
#pragma unroll
  for (int i = 0; i < 10; ++i) {
    int v = (base + i < N_NODES) ? cnt[base + i] : 0;
    local[i] = tot;
    tot += v;
  }
  sums[t] = tot;
  __syncthreads();
  for (int off = 1; off < 1024; off <<= 1) {
    int v = (t >= off) ? sums[t - off] : 0;
    __syncthreads();
    sums[t] += v;
    __syncthreads();
  }
  int excl = (t == 0) ? 0 : sums[t - 1];
#pragma unroll
  for (int i = 0; i < 10; ++i) {
    int idx = base + i;
    if (idx < N_NODES) {
      offsets[idx] = excl + local[i];
      cursor[idx] = excl + local[i];
    }
  }
  if (t == 1023) offsets[N_NODES] = sums[1023];
}

__global__ __launch_bounds__(256) void scatter_kernel(const int* __restrict__ edge_index,
                                                      int* __restrict__ cursor,
                                                      int* __restrict__ order,
                                                      int* __restrict__ rank) {
  int e = blockIdx.x * 256 + threadIdx.x;
  if (e >= E_TOTAL) return;
  int t = edge_index[E_TOTAL + e];
  int pos = atomicAdd(&cursor[t], 1);
  order[pos] = e;
  rank[e] = pos;
}

// ---------------- phase 1: per-edge MLP, write bf16 x[5][64] at sorted position ----------------
__global__ __launch_bounds__(256) void edge_mlp(
    const int* __restrict__ atomic_numbers,
    const float* __restrict__ edge_distance,
    const int* __restrict__ edge_index,
    const float* __restrict__ envelope,
    const float* __restrict__ w0,
    const float* __restrict__ b0,
    const float* __restrict__ g0,
    const float* __restrict__ beta0,
    const float* __restrict__ w1,
    const float* __restrict__ b1,
    const float* __restrict__ g1,
    const float* __restrict__ beta1,
    const float* __restrict__ w2,
    const float* __restrict__ b2,
    const float* __restrict__ pre,
    const int* __restrict__ rank,
    __hip_bfloat162* __restrict__ xr2) {
  __shared__ float sHa[TE * 128];
  __shared__ float sHb[TE * 128];
  __shared__ int s_srow[TE];
  __shared__ int s_trow[TE];
  __shared__ int s_rank[TE];
  __shared__ float s_env[TE];

  const int tid = threadIdx.x;
  const int eg = tid >> 5;
  const int cg = tid & 31;
  const int eBlock = blockIdx.x * TE;
  const int eL0 = eg * 4;
  const int c0 = cg * 4;

  if (tid < TE) {
    int e = eBlock + tid;
    s_srow[tid] = atomic_numbers[edge_index[e]];
    s_trow[tid] = atomic_numbers[edge_index[E_TOTAL + e]];
    s_rank[tid] = rank[e];
    s_env[tid] = envelope[e] * 0.2f;  // fold 1/RESCALE
  }
  {
    const float4* src4 = (const float4*)(edge_distance + (size_t)eBlock * 128);
    float4* dst4 = (float4*)sHb;
#pragma unroll
    for (int j = 0; j < 4; ++j) dst4[tid + 256 * j] = src4[tid + 256 * j];
  }
  __syncthreads();

  // GEMM1: dist @ w0[0:128]
  float acc[4][4];
#pragma unroll
  for (int i = 0; i < 4; ++i)
#pragma unroll
    for (int j = 0; j < 4; ++j) acc[i][j] = 0.f;
#pragma unroll 4
  for (int k = 0; k < 128; ++k) {
    float4 b = *(const float4*)(w0 + (size_t)k * 128 + c0);
    float a0 = sHb[(eL0 + 0) * 128 + k];
    float a1 = sHb[(eL0 + 1) * 128 + k];
    float a2 = sHb[(eL0 + 2) * 128 + k];
    float a3 = sHb[(eL0 + 3) * 128 + k];
    acc[0][0] += a0 * b.x; acc[0][1] += a0 * b.y; acc[0][2] += a0 * b.z; acc[0][3] += a0 * b.w;
    acc[1][0] += a1 * b.x; acc[1][1] += a1 * b.y; acc[1][2] += a1 * b.z; acc[1][3] += a1 * b.w;
    acc[2][0] += a2 * b.x; acc[2][1] += a2 * b.y; acc[2][2] += a2 * b.z; acc[2][3] += a2 * b.w;
    acc[3][0] += a3 * b.x; acc[3][1] += a3 * b.y; acc[3][2] += a3 * b.z; acc[3][3] += a3 * b.w;
  }
  __syncthreads();

  {
    float4 bb = *(const float4*)(b0 + c0);
#pragma unroll
    for (int i = 0; i < 4; ++i) {
      float4 ps = *(const float4*)(pre + (size_t)s_srow[eL0 + i] * 128 + c0);
      float4 pt = *(const float4*)(pre + PRE_T_OFF + (size_t)s_trow[eL0 + i] * 128 + c0);
      acc[i][0] += ps.x + pt.x + bb.x;
      acc[i][1] += ps.y + pt.y + bb.y;
      acc[i][2] += ps.z + pt.z + bb.z;
      acc[i][3] += ps.w + pt.w + bb.w;
    }
    float mu[4], rstd[4];
    ln_stats(acc, mu, rstd);
    float4 g = *(const float4*)(g0 + c0);
    float4 be = *(const float4*)(beta0 + c0);
#pragma unroll
    for (int i = 0; i < 4; ++i) {
      float v0 = silu_f((acc[i][0] - mu[i]) * rstd[i] * g.x + be.x);
      float v1 = silu_f((acc[i][1] - mu[i]) * rstd[i] * g.y + be.y);
      float v2 = silu_f((acc[i][2] - mu[i]) * rstd[i] * g.z + be.z);
      float v3 = silu_f((acc[i][3] - mu[i]) * rstd[i] * g.w + be.w);
      *(float4*)(sHa + (eL0 + i) * 128 + c0) = make_float4(v0, v1, v2, v3);
    }
  }
  __syncthreads();

  // GEMM2: h @ w1
#pragma unroll
  for (int i = 0; i < 4; ++i)
#pragma unroll
    for (int j = 0; j < 4; ++j) acc[i][j] = 0.f;
#pragma unroll 4
  for (int k = 0; k < 128; ++k) {
    float4 b = *(const float4*)(w1 + (size_t)k * 128 + c0);
    float a0 = sHa[(eL0 + 0) * 128 + k];
    float a1 = sHa[(eL0 + 1) * 128 + k];
    float a2 = sHa[(eL0 + 2) * 128 + k];
    float a3 = sHa[(eL0 + 3) * 128 + k];
    acc[0][0] += a0 * b.x; acc[0][1] += a0 * b.y; acc[0][2] += a0 * b.z; acc[0][3] += a0 * b.w;
    acc[1][0] += a1 * b.x; acc[1][1] += a1 * b.y; acc[1][2] += a1 * b.z; acc[1][3] += a1 * b.w;
    acc[2][0] += a2 * b.x; acc[2][1] += a2 * b.y; acc[2][2] += a2 * b.z; acc[2][3] += a2 * b.w;
    acc[3][0] += a3 * b.x; acc[3][1] += a3 * b.y; acc[3][2] += a3 * b.z; acc[3][3] += a3 * b.w;
  }
  {
    float4 bb = *(const float4*)(b1 + c0);
#pragma unroll
    for (int i = 0; i < 4; ++i) {
      acc[i][0] += bb.x; acc[i][1] += bb.y; acc[i][2] += bb.z; acc[i][3] += bb.w;
    }
    float mu[4], rstd[4];
    ln_stats(acc, mu, rstd);
    float4 g = *(const float4*)(g1 + c0);
    float4 be = *(const float4*)(beta1 + c0);
#pragma unroll
    for (int i = 0; i < 4; ++i) {
      float v0 = silu_f((acc[i][0] - mu[i]) * rstd[i] * g.x + be.x);
      float v1 = silu_f((acc[i][1] - mu[i]) * rstd[i] * g.y + be.y);
      float v2 = silu_f((acc[i][2] - mu[i]) * rstd[i] * g.z + be.z);
      float v3 = silu_f((acc[i][3] - mu[i]) * rstd[i] * g.w + be.w);
      *(float4*)(sHb + (eL0 + i) * 128 + c0) = make_float4(v0, v1, v2, v3);
    }
  }
  __syncthreads();

  // GEMM3: h2 @ w2 (128x320); thread: 4 edges x 5 l x 2 c
  const int c2 = cg * 2;
  float acc3[4][5][2];
#pragma unroll
  for (int i = 0; i < 4; ++i)
#pragma unroll
    for (int l = 0; l < 5; ++l) { acc3[i][l][0] = 0.f; acc3[i][l][1] = 0.f; }
#pragma unroll 2
  for (int k = 0; k < 128; ++k) {
    float a0 = sHb[(eL0 + 0) * 128 + k];
    float a1 = sHb[(eL0 + 1) * 128 + k];
    float a2 = sHb[(eL0 + 2) * 128 + k];
    float a3 = sHb[(eL0 + 3) * 128 + k];
#pragma unroll
    for (int l = 0; l < 5; ++l) {
      float2 b = *(const float2*)(w2 + (size_t)k * 320 + l * 64 + c2);
      acc3[0][l][0] += a0 * b.x; acc3[0][l][1] += a0 * b.y;
      acc3[1][l][0] += a1 * b.x; acc3[1][l][1] += a1 * b.y;
      acc3[2][l][0] += a2 * b.x; acc3[2][l][1] += a2 * b.y;
      acc3[3][l][0] += a3 * b.x; acc3[3][l][1] += a3 * b.y;
    }
  }

  // bias + envelope, write bf16 at rank-sorted position
#pragma unroll
  for (int i = 0; i < 4; ++i) {
    float ev = s_env[eL0 + i];
    size_t pos = (size_t)s_rank[eL0 + i];
#pragma unroll
    for (int l = 0; l < 5; ++l) {
      float2 bb = *(const float2*)(b2 + l * 64 + c2);
      __hip_bfloat162 v;
      v.x = __float2bfloat16((acc3[i][l][0] + bb.x) * ev);
      v.y = __float2bfloat16((acc3[i][l][1] + bb.y) * ev);
      xr2[pos * 160 + l * 32 + cg] = v;
    }
  }
}

// ---------------- phase 2: per-node gather + wigner rotate, single write ----------------
__global__ __launch_bounds__(320) void node_gather(
    const int* __restrict__ offsets,
    const int* __restrict__ order,
    const __hip_bfloat162* __restrict__ xr2,
    const float* __restrict__ wig,
    float* __restrict__ out) {
  const int nid = blockIdx.x;
  const int tid = threadIdx.x;
  const int c = tid & 63;
  const int mb = tid >> 6;  // 0..4
  __shared__ float xS[320];
  __shared__ float wS[128];

  int start = offsets[nid];
  int end = offsets[nid + 1];
  float acc[5] = {0.f, 0.f, 0.f, 0.f, 0.f};

  for (int i = start; i < end; ++i) {
    int e = order[i];
    if (tid < 160) {
      __hip_bfloat162 v = xr2[(size_t)i * 160 + tid];
      xS[2 * tid] = __bfloat162float(v.x);
      xS[2 * tid + 1] = __bfloat162float(v.y);
    } else if (tid < 160 + 125) {
      int r = tid - 160;
      int m = r / 5;
      int l = r - 5 * m;
      wS[r] = wig[(size_t)e * 625 + m * 25 + l];
    }
    __syncthreads();
    float x0 = xS[0 * 64 + c];
    float x1 = xS[1 * 64 + c];
    float x2 = xS[2 * 64 + c];
    float x3 = xS[3 * 64 + c];
    float x4 = xS[4 * 64 + c];
#pragma unroll
    for (int j = 0; j < 5; ++j) {
      const float* w = &wS[(mb * 5 + j) * 5];
      acc[j] += w[0] * x0 + w[1] * x1 + w[2] * x2 + w[3] * x3 + w[4] * x4;
    }
    __syncthreads();
  }
  float* po = out + (size_t)nid * 1600;
#pragma unroll
  for (int j = 0; j < 5; ++j) po[(mb * 5 + j) * 64 + c] = acc[j];
}

// ---------------- fallback: round-1 atomic kernel (used only if ws too small) ----------------
__global__ __launch_bounds__(256) void edge_fused_atomic(
    const int* __restrict__ atomic_numbers,
    const float* __restrict__ edge_distance,
    const int* __restrict__ edge_index,
    const float* __restrict__ envelope,
    const float* __restrict__ w0,
    const float* __restrict__ b0,
    const float* __restrict__ g0,
    const float* __restrict__ beta0,
    const float* __restrict__ w1,
    const float* __restrict__ b1,
    const float* __restrict__ g1,
    const float* __restrict__ beta1,
    const float* __restrict__ w2,
    const float* __restrict__ b2,
    const float* __restrict__ wig,
    const float* __restrict__ pre,
    float* __restrict__ out) {
  __shared__ float sHa[TE * 128];
  __shared__ float sHb[TE * 128];
  __shared__ int s_srow[TE];
  __shared__ int s_trow[TE];
  __shared__ int s_tgt[TE];
  __shared__ float s_env[TE];

  const int tid = threadIdx.x;
  const int eg = tid >> 5;
  const int cg = tid & 31;
  const int eBlock = blockIdx.x * TE;
  const int eL0 = eg * 4;
  const int c0 = cg * 4;

  if (tid < TE) {
    int e = eBlock + tid;
    int dst = edge_index[E_TOTAL + e];
    s_srow[tid] = atomic_numbers[edge_index[e]];
    s_trow[tid] = atomic_numbers[dst];
    s_tgt[tid] = dst;
    s_env[tid] = envelope[e] * 0.2f;
  }
  {
    const float4* src4 = (const float4*)(edge_distance + (size_t)eBlock * 128);
    float4* dst4 = (float4*)sHb;
#pragma unroll
    for (int j = 0; j < 4; ++j) dst4[tid + 256 * j] = src4[tid + 256 * j];
  }
  __syncthreads();

  float acc[4][4];
#pragma unroll
  for (int i = 0; i < 4; ++i)
#pragma unroll
    for (int j = 0; j < 4; ++j) acc[i][j] = 0.f;
#pragma unroll 4
  for (int k = 0; k < 128; ++k) {
    float4 b = *(const float4*)(w0 + (size_t)k * 128 + c0);
    float a0 = sHb[(eL0 + 0) * 128 + k];
    float a1 = sHb[(eL0 + 1) * 128 + k];
    float a2 = sHb[(eL0 + 2) * 128 + k];
    float a3 = sHb[(eL0 + 3) * 128 + k];
    acc[0][0] += a0 * b.x; acc[0][1] += a0 * b.y; acc[0][2] += a0 * b.z; acc[0][3] += a0 * b.w;
    acc[1][0] += a1 * b.x; acc[1][1] += a1 * b.y; acc[1][2] += a1 * b.z; acc[1][3] += a1 * b.w;
    acc[2][0] += a2 * b.x; acc[2][1] += a2 * b.y; acc[2][2] += a2 * b.z; acc[2][3] += a2 * b.w;
    acc[3][0] += a3 * b.x; acc[3][1] += a3 * b.y; acc[3][2] += a3 * b.z; acc[3][3] += a3 * b.w;
  }
  __syncthreads();

  {
    float4 bb = *(const float4*)(b0 + c0);
#pragma unroll
    for (int i = 0; i < 4; ++i) {
      float4 ps = *(const float4*)(pre + (size_t)s_srow[eL0 + i] * 128 + c0);
      float4 pt = *(const float4*)(pre + PRE_T_OFF + (size_t)s_trow[eL0 + i] * 128 + c0);
      acc[i][0] += ps.x + pt.x + bb.x;
      acc[i][1] += ps.y + pt.y + bb.y;
      acc[i][2] += ps.z + pt.z + bb.z;
      acc[i][3] += ps.w + pt.w + bb.w;
    }
    float mu[4], rstd[4];
    ln_stats(acc, mu, rstd);
    float4 g = *(const float4*)(g0 + c0);
    float4 be = *(const float4*)(beta0 + c0);
#pragma unroll
    for (int i = 0; i < 4; ++i) {
      float v0 = silu_f((acc[i][0] - mu[i]) * rstd[i] * g.x + be.x);
      float v1 = silu_f((acc[i][1] - mu[i]) * rstd[i] * g.y + be.y);
      float v2 = silu_f((acc[i][2] - mu[i]) * rstd[i] * g.z + be.z);
      float v3 = silu_f((acc[i][3] - mu[i]) * rstd[i] * g.w + be.w);
      *(float4*)(sHa + (eL0 + i) * 128 + c0) = make_float4(v0, v1, v2, v3);
    }
  }
  __syncthreads();

#pragma unroll
  for (int i = 0; i < 4; ++i)
#pragma unroll
    for (int j = 0; j < 4; ++j) acc[i][j] = 0.f;
#pragma unroll 4
  for (int k = 0; k < 128; ++k) {
    float4 b = *(const float4*)(w1 + (size_t)k * 128 + c0);
    float a0 = sHa[(eL0 + 0) * 128 + k];
    float a1 = sHa[(eL0 + 1) * 128 + k];
    float a2 = sHa[(eL0 + 2) * 128 + k];
    float a3 = sHa[(eL0 + 3) * 128 + k];
    acc[0][0] += a0 * b.x; acc[0][1] += a0 * b.y; acc[0][2] += a0 * b.z; acc[0][3] += a0 * b.w;
    acc[1][0] += a1 * b.x; acc[1][1] += a1 * b.y; acc[1][2] += a1 * b.z; acc[1][3] += a1 * b.w;
    acc[2][0] += a2 * b.x; acc[2][1] += a2 * b.y; acc[2][2] += a2 * b.z; acc[2][3] += a2 * b.w;
    acc[3][0] += a3 * b.x; acc[3][1] += a3 * b.y; acc[3][2] += a3 * b.z; acc[3][3] += a3 * b.w;
  }
  {
    float4 bb = *(const float4*)(b1 + c0);
#pragma unroll
    for (int i = 0; i < 4; ++i) {
      acc[i][0] += bb.x; acc[i][1] += bb.y; acc[i][2] += bb.z; acc[i][3] += bb.w;
    }
    float mu[4], rstd[4];
    ln_stats(acc, mu, rstd);
    float4 g = *(const float4*)(g1 + c0);
    float4 be = *(const float4*)(beta1 + c0);
#pragma unroll
    for (int i = 0; i < 4; ++i) {
      float v0 = silu_f((acc[i][0] - mu[i]) * rstd[i] * g.x + be.x);
      float v1 = silu_f((acc[i][1] - mu[i]) * rstd[i] * g.y + be.y);
      float v2 = silu_f((acc[i][2] - mu[i]) * rstd[i] * g.z + be.z);
      float v3 = silu_f((acc[i][3] - mu[i]) * rstd[i] * g.w + be.w);
      *(float4*)(sHb + (eL0 + i) * 128 + c0) = make_float4(v0, v1, v2, v3);
    }
  }
  __syncthreads();

  float* sW = sHa;
  for (int j = tid; j < TE * 125; j += 256) {
    int e = j / 125;
    int r = j - e * 125;
    int m = r / 5;
    int l = r - m * 5;
    sW[j] = wig[(size_t)(eBlock + e) * 625 + m * 25 + l];
  }

  const int c2 = cg * 2;
  float acc3[4][5][2];
#pragma unroll
  for (int i = 0; i < 4; ++i)
#pragma unroll
    for (int l = 0; l < 5; ++l) { acc3[i][l][0] = 0.f; acc3[i][l][1] = 0.f; }
#pragma unroll 2
  for (int k = 0; k < 128; ++k) {
    float a0 = sHb[(eL0 + 0) * 128 + k];
    float a1 = sHb[(eL0 + 1) * 128 + k];
    float a2 = sHb[(eL0 + 2) * 128 + k];
    float a3 = sHb[(eL0 + 3) * 128 + k];
#pragma unroll
    for (int l = 0; l < 5; ++l) {
      float2 b = *(const float2*)(w2 + (size_t)k * 320 + l * 64 + c2);
      acc3[0][l][0] += a0 * b.x; acc3[0][l][1] += a0 * b.y;
      acc3[1][l][0] += a1 * b.x; acc3[1][l][1] += a1 * b.y;
      acc3[2][l][0] += a2 * b.x; acc3[2][l][1] += a2 * b.y;
      acc3[3][l][0] += a3 * b.x; acc3[3][l][1] += a3 * b.y;
    }
  }

#pragma unroll
  for (int l = 0; l < 5; ++l) {
    float2 bb = *(const float2*)(b2 + l * 64 + c2);
#pragma unroll
    for (int i = 0; i < 4; ++i) {
      float ev = s_env[eL0 + i];
      acc3[i][l][0] = (acc3[i][l][0] + bb.x) * ev;
      acc3[i][l][1] = (acc3[i][l][1] + bb.y) * ev;
    }
  }
  __syncthreads();

#pragma unroll
  for (int i = 0; i < 4; ++i) {
    float* po = out + (size_t)s_tgt[eL0 + i] * 1600 + c2;
    const float* pw = sW + (eL0 + i) * 125;
    for (int m = 0; m < 25; ++m) {
      float wv0 = pw[m * 5 + 0];
      float wv1 = pw[m * 5 + 1];
      float wv2 = pw[m * 5 + 2];
      float wv3 = pw[m * 5 + 3];
      float wv4 = pw[m * 5 + 4];
      float y0 = wv0 * acc3[i][0][0] + wv1 * acc3[i][1][0] + wv2 * acc3[i][2][0] +
                 wv3 * acc3[i][3][0] + wv4 * acc3[i][4][0];
      float y1 = wv0 * acc3[i][0][1] + wv1 * acc3[i][1][1] + wv2 * acc3[i][2][1] +
                 wv3 * acc3[i][3][1] + wv4 * acc3[i][4][1];
      __hip_atomic_fetch_add(po + m * 64, y0, __ATOMIC_RELAXED, __HIP_MEMORY_SCOPE_AGENT);
      __hip_atomic_fetch_add(po + m * 64 + 1, y1, __ATOMIC_RELAXED, __HIP_MEMORY_SCOPE_AGENT);
    }
  }
}

extern "C" void kernel_launch(void* const* d_in, const int* in_sizes, int n_in,
                              void* d_out, int out_size, void* d_ws, size_t ws_size,
                              hipStream_t stream) {
  const int* atomic_numbers = (const int*)d_in[0];
  const float* edge_distance = (const float*)d_in[1];
  const int* edge_index = (const int*)d_in[2];
  const float* envelope = (const float*)d_in[3];
  const float* source_emb = (const float*)d_in[4];
  const float* target_emb = (const float*)d_in[5];
  const float* w0 = (const float*)d_in[6];
  const float* b0 = (const float*)d_in[7];
  const float* g0 = (const float*)d_in[8];
  const float* beta0 = (const float*)d_in[9];
  const float* w1 = (const float*)d_in[10];
  const float* b1 = (const float*)d_in[11];
  const float* g1 = (const float*)d_in[12];
  const float* beta1 = (const float*)d_in[13];
  const float* w2 = (const float*)d_in[14];
  const float* b2 = (const float*)d_in[15];
  const float* wig = (const float*)d_in[16];
  float* out = (float*)d_out;

  // ws layout (256B-aligned regions)
  char* ws = (char*)d_ws;
  float* pre = (float*)(ws + 0);                  //  92160 B
  int* cnt = (int*)(ws + 92160);                  //  40000 B
  int* offsets = (int*)(ws + 132352);             //  40004 B
  int* cursor = (int*)(ws + 172544);              //  40000 B
  int* order = (int*)(ws + 212736);               // 640000 B
  int* rank = (int*)(ws + 852736);                // 640000 B
  __hip_bfloat162* xr2 = (__hip_bfloat162*)(ws + 1492736);  // 102400000 B
  const size_t WS_NEED = 1492736 + (size_t)E_TOTAL * 320 * 2;

  precompute_embw<<<(2 * NELEM_ * 128 + 255) / 256, 256, 0, stream>>>(
      source_emb, target_emb, w0, pre);

  if (ws_size >= WS_NEED) {
    hipMemsetAsync(cnt, 0, N_NODES * sizeof(int), stream);
    count_kernel<<<(E_TOTAL + 255) / 256, 256, 0, stream>>>(edge_index, cnt);
    scan_kernel<<<1, 1024, 0, stream>>>(cnt, offsets, cursor);
    scatter_kernel<<<(E_TOTAL + 255) / 256, 256, 0, stream>>>(edge_index, cursor, order, rank);
    edge_mlp<<<E_TOTAL / TE, 256, 0, stream>>>(
        atomic_numbers, edge_distance, edge_index, envelope, w0, b0, g0, beta0,
        w1, b1, g1, beta1, w2, b2, pre, rank, xr2);
    node_gather<<<N_NODES, 320, 0, stream>>>(offsets, order, xr2, wig, out);
  } else {
    hipMemsetAsync(d_out, 0, (size_t)out_size * sizeof(float), stream);
    edge_fused_atomic<<<E_TOTAL / TE, 256, 0, stream>>>(
        atomic_numbers, edge_distance, edge_index, envelope, w0, b0, g0, beta0,
        w1, b1, g1, beta1, w2, b2, wig, pre, out);
  }
}